// Round 5
// baseline (322.731 us; speedup 1.0000x reference)
//
#include <hip/hip_runtime.h>
#include <hip/hip_bf16.h>
#include <float.h>

// Problem constants (fixed by the reference)
constexpr int NENT  = 100000;
constexpr int DDIM  = 256;
constexpr int BQ    = 64;
constexpr int CANDN = 10000;
constexpr int KTOP  = 10;
constexpr int NSLICE = 16;
constexpr int SLICE  = 6272;    // 16*6272 = 100352 >= NENT, multiple of 4
constexpr int HPAD   = 132;     // histG per-(b,s) stride

typedef short v8s __attribute__((ext_vector_type(8)));   // 8 bf16 (4 VGPRs)
typedef float v4f __attribute__((ext_vector_type(4)));   // MFMA accumulator

// 3-way split: x ~= b0 + b1 + b2 (bf16 each), residual ~2^-21 |x|
__device__ inline void split3(float x, unsigned short& h0, unsigned short& h1,
                              unsigned short& h2) {
    unsigned t0 = __float_as_uint(x) & 0xffff0000u;
    float r1 = x - __uint_as_float(t0);
    unsigned t1 = __float_as_uint(r1) & 0xffff0000u;
    float r2 = r1 - __uint_as_float(t1);
    h0 = (unsigned short)(t0 >> 16);
    h1 = (unsigned short)(t1 >> 16);
    h2 = (unsigned short)(__float_as_uint(r2) >> 16);
}

// split 8 fp32 (two float4 slots in LDS) into three bf16x8 fragments
__device__ inline void split8p(const float* p0, const float* p1,
                               v8s& o0, v8s& o1, v8s& o2) {
    union { v8s v; unsigned short u[8]; } r0, r1, r2;
    float4 f0 = *(const float4*)p0;
    float4 f1 = *(const float4*)(p1);
    float av[8] = {f0.x, f0.y, f0.z, f0.w, f1.x, f1.y, f1.z, f1.w};
    #pragma unroll
    for (int j = 0; j < 8; j++)
        split3(av[j], r0.u[j], r1.u[j], r2.u[j]);
    o0 = r0.v; o1 = r1.v; o2 = r2.v;
}

// async global->LDS, 16B per lane; LDS dest is wave-uniform base + lane*16
__device__ inline void stage16(const float* g, float* l) {
    __builtin_amdgcn_global_load_lds(
        (const __attribute__((address_space(1))) void*)g,
        (__attribute__((address_space(3))) void*)l, 16, 0, 0);
}

// ---------------------------------------------------------------------------
// K1 (fused): blocks 0..127: proj column -> W planes.
//             blocks 128..191: target b = blk-128 -> tgtT, W col 128+b, thash.
// ---------------------------------------------------------------------------
__global__ __launch_bounds__(256) void k_prep(
    const int* __restrict__ head, const int* __restrict__ rel,
    const float* __restrict__ E, const float* __restrict__ Rm,
    const float* __restrict__ proj,
    float* __restrict__ tgtT, unsigned* __restrict__ thash,
    unsigned short* __restrict__ Whi, unsigned short* __restrict__ Wmid,
    unsigned short* __restrict__ Wlo)
{
    __shared__ float tg[DDIM];
    int blk = blockIdx.x;
    int tid = threadIdx.x;    // 256, one d each
    if (blk < 128) {
        int c = blk, d = tid;
        float x = proj[((c >> 5)*DDIM + d)*32 + (c & 31)];
        unsigned short h0, h1, h2;
        split3(x, h0, h1, h2);
        Whi [c*DDIM + d] = h0;
        Wmid[c*DDIM + d] = h1;
        Wlo [c*DDIM + d] = h2;
    } else {
        int b = blk - 128;
        int h = head[b], r = rel[b];
        int d = tid;
        float v = E[h*DDIM + d] * Rm[r*DDIM + d];
        tg[d] = v;
        tgtT[d*BQ + b] = v;
        unsigned short h0, h1, h2;
        split3(v, h0, h1, h2);
        int c = 128 + b;
        Whi [c*DDIM + d] = h0;
        Wmid[c*DDIM + d] = h1;
        Wlo [c*DDIM + d] = h2;
        __syncthreads();
        if (tid < 128) {
            int t = tid >> 5, hh = tid & 31;
            float acc = 0.f;
            #pragma unroll 8
            for (int dd = 0; dd < DDIM; dd++)
                acc += tg[dd] * proj[(t*DDIM + dd)*32 + hh];
            unsigned long long m = __ballot(acc > 0.0f);
            int lane = tid & 63, w = tid >> 6;
            if (lane == 0) {
                thash[b*4 + w*2 + 0] = (unsigned)(m & 0xffffffffull);
                thash[b*4 + w*2 + 1] = (unsigned)(m >> 32);
            }
        }
    }
}

// ---------------------------------------------------------------------------
// K2: MFMA bf16x3 (6-product) GEMM.  out[n][c] = sum_d E[n][d] * W[c][d]
//   cols 0..127 -> sign bits packed to ahash[n][4]; cols 128..191 -> scores.
//
// v5: BK=64 (two 32-wide sub-chunks per iteration) -> 4 barriers/block
// instead of 8; 2x window for stage + B-load latency to hide. A tile
// (128x64 fp32) double-buffered via global_load_lds w=16 with 16B-unit XOR
// swizzle on the low 3 unit bits (slot v of row r holds source unit
// v^(r&7); global source pre-swizzled, LDS dest linear). B from global
// (L2-resident). Accumulation order per output identical to v1/R1.
// ---------------------------------------------------------------------------
constexpr int TILE_E = 128;

__global__ __launch_bounds__(256, 2) void k_gemm(
    const float* __restrict__ E,
    const unsigned short* __restrict__ Whi, const unsigned short* __restrict__ Wmid,
    const unsigned short* __restrict__ Wlo,
    unsigned* __restrict__ ahash, float* __restrict__ scores)
{
    __shared__ __align__(16) float Af[2][TILE_E*64];   // 2 x 32 KiB
    unsigned short* bitsHalf = (unsigned short*)Af;    // aliased after compute

    int tid = threadIdx.x;
    int l = tid & 63, w = tid >> 6;
    int wm = w >> 1, wn = w & 1;
    int m = l & 15, quad = l >> 4;
    int n0 = blockIdx.x * TILE_E;

    // --- per-thread staging source pointers (8 wave-instructions/iter) ---
    // linear LDS unit U = it*256 + tid; row = U>>4, slot v = U&15,
    // source unit = v ^ (row&7)   (XOR on low 3 bits only; involution)
    const float* gsrc[8];
    #pragma unroll
    for (int it = 0; it < 8; it++) {
        int U = it*256 + tid;           // 0..2047
        int row = U >> 4;               // 0..127
        int us  = (U & 15) ^ (row & 7);
        int n = n0 + row; if (n >= NENT) n = NENT - 1;
        gsrc[it] = E + (size_t)n*DDIM + us*4;
    }

    // --- A-fragment LDS read offsets (floats), conflict-free swizzled ---
    // float off = row*64 + (kk*8 + ((2*quad+j) ^ (m&7)))*4   (row&7 == m&7)
    int offA[4][2][2];
    #pragma unroll
    for (int a = 0; a < 4; a++) {
        int row = wm*64 + a*16 + m;
        #pragma unroll
        for (int kk = 0; kk < 2; kk++) {
            offA[a][kk][0] = row*64 + (kk*8 + (((2*quad)    ) ^ (m & 7)))*4;
            offA[a][kk][1] = row*64 + (kk*8 + (((2*quad) | 1) ^ (m & 7)))*4;
        }
    }

    // --- B column base offsets (halfwords into W planes) ---
    int colOff[6];
    #pragma unroll
    for (int c = 0; c < 6; c++)
        colOff[c] = (wn*96 + c*16 + m)*DDIM + quad*8;

    v4f acc[4][6];
    #pragma unroll
    for (int a = 0; a < 4; a++)
        #pragma unroll
        for (int c = 0; c < 6; c++)
            acc[a][c] = (v4f)0.0f;

    // prologue: stage iteration 0 (d = 0..63) into buffer 0
    #pragma unroll
    for (int it = 0; it < 8; it++)
        stage16(gsrc[it], &Af[0][(it*256 + w*64)*4]);
    __syncthreads();

    int bb = 0;
    for (int ch = 0; ch < DDIM/64; ch++) {
        // issue next-iteration stage first (hides under ~2 sub-chunks of work)
        if (ch + 1 < DDIM/64) {
            #pragma unroll
            for (int it = 0; it < 8; it++)
                stage16(gsrc[it] + (ch + 1)*64, &Af[bb ^ 1][(it*256 + w*64)*4]);
        }

        // two 32-wide sub-chunks from the same LDS buffer
        #pragma unroll
        for (int kk = 0; kk < 2; kk++) {
            v8s a0[4], a1[4], a2[4];
            #pragma unroll
            for (int a = 0; a < 4; a++)
                split8p(&Af[bb][offA[a][kk][0]], &Af[bb][offA[a][kk][1]],
                        a0[a], a1[a], a2[a]);

            int d0 = ch*64 + kk*32;
            #pragma unroll
            for (int c = 0; c < 6; c++) {
                int co = colOff[c] + d0;
                v8s b0 = *(const v8s*)(Whi  + co);
                v8s b1 = *(const v8s*)(Wmid + co);
                v8s b2 = *(const v8s*)(Wlo  + co);
                #pragma unroll
                for (int a = 0; a < 4; a++) {
                    acc[a][c] = __builtin_amdgcn_mfma_f32_16x16x32_bf16(a2[a], b0, acc[a][c], 0, 0, 0);
                    acc[a][c] = __builtin_amdgcn_mfma_f32_16x16x32_bf16(a0[a], b2, acc[a][c], 0, 0, 0);
                    acc[a][c] = __builtin_amdgcn_mfma_f32_16x16x32_bf16(a1[a], b1, acc[a][c], 0, 0, 0);
                    acc[a][c] = __builtin_amdgcn_mfma_f32_16x16x32_bf16(a1[a], b0, acc[a][c], 0, 0, 0);
                    acc[a][c] = __builtin_amdgcn_mfma_f32_16x16x32_bf16(a0[a], b1, acc[a][c], 0, 0, 0);
                    acc[a][c] = __builtin_amdgcn_mfma_f32_16x16x32_bf16(a0[a], b0, acc[a][c], 0, 0, 0);
                }
            }
        }
        __syncthreads();   // drains vmcnt(0): next buffer staged + safe reuse
        bb ^= 1;
    }

    // ---- epilogue: C/D layout col=lane&15, row=quad*4+reg ----
    #pragma unroll
    for (int c = 0; c < 6; c++) {
        int ct = wn*6 + c;                 // global col-tile 0..11
        if (ct < 8) {
            #pragma unroll
            for (int a = 0; a < 4; a++) {
                #pragma unroll
                for (int r = 0; r < 4; r++) {
                    unsigned long long mb = __ballot(acc[a][c][r] > 0.0f);
                    if (m == 0) {
                        int rowl = wm*64 + a*16 + quad*4 + r;
                        bitsHalf[rowl*8 + ct] = (unsigned short)(mb >> (quad*16));
                    }
                }
            }
        } else {
            int b = ct*16 - 128 + m;       // query index 0..63
            #pragma unroll
            for (int a = 0; a < 4; a++) {
                int nb = n0 + wm*64 + a*16 + quad*4;
                if (nb < NENT)
                    *(float4*)(scores + (size_t)b*NENT + nb) = *(float4*)&acc[a][c];
            }
        }
    }
    __syncthreads();
    if (tid < TILE_E) {
        int n = n0 + tid;
        if (n < NENT)
            *(uint4*)(ahash + (size_t)n*4) = *(const uint4*)&bitsHalf[tid*8];
    }
}

// ---------------------------------------------------------------------------
// K3a: per-(query,slice) distance bytes + slice histogram.
// 8-way lane-interleaved histograms (hist[bin][tid&7]): same-address
// serialization within a wave atomic drops to <=8-way; the 8 copies of a
// bin sit in 8 consecutive banks.
// ---------------------------------------------------------------------------
__global__ __launch_bounds__(256) void k_dist(
    const unsigned* __restrict__ ahash, const unsigned* __restrict__ thash,
    unsigned char* __restrict__ dist8, unsigned short* __restrict__ histG)
{
    __shared__ unsigned hist[HPAD][8];
    int s = blockIdx.x, b = blockIdx.y, tid = threadIdx.x;
    int lv = tid & 7;
    for (int i = tid; i < 8*HPAD; i += 256) ((unsigned*)hist)[i] = 0u;
    uint4 tw = *(const uint4*)(thash + b*4);
    __syncthreads();
    int n0 = s*SLICE;
    int n1 = n0 + SLICE; if (n1 > NENT) n1 = NENT;
    unsigned char* drow = dist8 + (size_t)b*NENT;
    for (int n = n0 + tid*4; n < n1; n += 1024) {
        int dv[4];
        #pragma unroll
        for (int i = 0; i < 4; i++) {
            uint4 a = *(const uint4*)(ahash + (size_t)(n+i)*4);
            dv[i] = __popc(a.x^tw.x) + __popc(a.y^tw.y) +
                    __popc(a.z^tw.z) + __popc(a.w^tw.w);
            atomicAdd(&hist[dv[i]][lv], 1u);
        }
        uchar4 o = make_uchar4((unsigned char)dv[0], (unsigned char)dv[1],
                               (unsigned char)dv[2], (unsigned char)dv[3]);
        *(uchar4*)(drow + n) = o;
    }
    __syncthreads();
    unsigned short* hrow = histG + ((size_t)b*NSLICE + s)*HPAD;
    for (int i = tid; i < 129; i += 256) {
        unsigned t = 0;
        #pragma unroll
        for (int v = 0; v < 8; v++) t += hist[i][v];
        hrow[i] = (unsigned short)t;
    }
}

// ---------------------------------------------------------------------------
// K3b: per-query: total histogram -> d*, quota R; slice prefix -> nCut.
// Scan reads 256 entities/iter (4 x 64B loads) with in-order 64-wide ballots.
// ---------------------------------------------------------------------------
__global__ __launch_bounds__(64) void k_cut(
    const unsigned char* __restrict__ dist8, const unsigned short* __restrict__ histG,
    int* __restrict__ dsG, int* __restrict__ ncG)
{
    __shared__ unsigned histT[HPAD];
    __shared__ int dsS, slS, rpS;
    int b = blockIdx.x, tid = threadIdx.x;
    for (int d = tid; d < 129; d += 64) {
        unsigned sum = 0;
        for (int s = 0; s < NSLICE; s++)
            sum += histG[((size_t)b*NSLICE + s)*HPAD + d];
        histT[d] = sum;
    }
    __syncthreads();
    if (tid == 0) {
        unsigned cum = 0; int ds = 128; unsigned R = 1;
        for (int d = 0; d < 129; d++) {
            unsigned c = cum + histT[d];
            if (c >= (unsigned)CANDN) { ds = d; R = (unsigned)CANDN - cum; break; }
            cum = c;
        }
        dsS = ds; dsG[b] = ds;
        unsigned acc = 0;
        for (int s = 0; s < NSLICE; s++) {
            unsigned c = histG[((size_t)b*NSLICE + s)*HPAD + ds];
            if (acc + c >= R) { slS = s; rpS = (int)(R - acc); break; }
            acc += c;
        }
    }
    __syncthreads();
    int ds = dsS;
    unsigned Rp = (unsigned)rpS;
    const unsigned char* drow = dist8 + (size_t)b*NENT;
    int sBase = slS*SLICE;
    int sEnd = sBase + SLICE; if (sEnd > NENT) sEnd = NENT;
    unsigned cnt = 0;
    for (int base = sBase; base < sEnd; base += 256) {
        unsigned char qa[4];
        #pragma unroll
        for (int s4 = 0; s4 < 4; s4++) {
            int n = base + s4*64 + tid;
            qa[s4] = (n < sEnd) ? drow[n] : (unsigned char)255;
        }
        bool done = false;
        #pragma unroll
        for (int s4 = 0; s4 < 4; s4++) {
            bool eq = (qa[s4] == (unsigned char)ds);
            unsigned long long mm = __ballot(eq);
            unsigned c = __popcll(mm);
            if (cnt + c >= Rp) {
                unsigned pre = __popcll(mm & ((1ull << tid) - 1ull));
                if (eq && (cnt + pre + 1u == Rp)) ncG[b] = base + s4*64 + tid;
                done = true; break;
            }
            cnt += c;
        }
        if (done) break;
    }
}

// ---------------------------------------------------------------------------
// K4a: per-(query, slice) top-10 pool builder via 3-barrier threshold
// selection + EXACT fp32 rescore of the 10 slice winners.
// ---------------------------------------------------------------------------
__global__ __launch_bounds__(256) void k_part(
    const unsigned char* __restrict__ dist8, const float* __restrict__ scores,
    const int* __restrict__ dsG, const int* __restrict__ ncG,
    const float* __restrict__ tgtT, const float* __restrict__ E,
    float* __restrict__ partS, int* __restrict__ partI)
{
    __shared__ float ls[256];
    __shared__ int   li[256];
    __shared__ float ps[112];
    __shared__ int   pi[112];
    __shared__ int   pcnt;
    __shared__ float TsS; __shared__ int TiS;
    __shared__ int   chosenI[KTOP];
    __shared__ float tgl[DDIM];

    int sl = blockIdx.x, b = blockIdx.y, tid = threadIdx.x;
    int ds = dsG[b], nc = ncG[b];
    const unsigned char* drow = dist8 + (size_t)b*NENT;
    const float* srow = scores + (size_t)b*NENT;
    int n0 = sl*SLICE;
    int n1 = n0 + SLICE; if (n1 > NENT) n1 = NENT;

    float topS[KTOP]; int topI[KTOP];
    #pragma unroll
    for (int i = 0; i < KTOP; i++) { topS[i] = -FLT_MAX; topI[i] = 0x7fffffff; }

    for (int n = n0 + tid*4; n < n1; n += 1024) {
        uchar4 dv = *(const uchar4*)(drow + n);
        unsigned char da[4] = {dv.x, dv.y, dv.z, dv.w};
        #pragma unroll
        for (int i = 0; i < 4; i++) {
            int d = da[i];
            int nn = n + i;
            if (d < ds || (d == ds && nn <= nc)) {
                float sc = srow[nn];
                if (sc > topS[KTOP-1]) {
                    int p = KTOP - 1;
                    while (p > 0 && topS[p-1] < sc) {
                        topS[p] = topS[p-1]; topI[p] = topI[p-1]; p--;
                    }
                    topS[p] = sc; topI[p] = nn;
                }
            }
        }
    }

    // ---- threshold selection ----
    ls[tid] = topS[0]; li[tid] = topI[0];
    if (tid == 0) pcnt = 0;
    if (tid < 112) { ps[tid] = -FLT_MAX; pi[tid] = 0x7fffffff; }
    __syncthreads();

    float mv = topS[0]; int mi = topI[0];
    int rank = 0;
    for (int i = 0; i < 256; i++) {
        float v = ls[i]; int id = li[i];
        rank += (v > mv || (v == mv && id < mi)) ? 1 : 0;
    }
    if (rank == 9 || (rank < 9 && mi == 0x7fffffff)) { TsS = mv; TiS = mi; }
    __syncthreads();
    float ts = TsS; int ti = TiS;

    if (!(ts > mv || (ts == mv && ti < mi))) {
        #pragma unroll
        for (int j = 0; j < KTOP; j++) {
            float sj = topS[j]; int ij = topI[j];
            if (ij == 0x7fffffff) break;
            if (sj > ts || (sj == ts && ij <= ti)) {
                int p = atomicAdd(&pcnt, 1);
                ps[p] = sj; pi[p] = ij;
            } else break;
        }
    }
    __syncthreads();

    if (tid < 112) {
        float s = ps[tid]; int id = pi[tid];
        int r = 0;
        for (int i = 0; i < 112; i++) {
            float v = ps[i]; int iv = pi[i];
            bool beats = (v > s) || (v == s && (iv < id || (iv == id && i < tid)));
            r += beats ? 1 : 0;
        }
        if (r < KTOP) {
            chosenI[r] = id;
            partI[((size_t)b*NSLICE + sl)*KTOP + r] = id;
        }
    }

    for (int d = tid; d < DDIM; d += 256) tgl[d] = tgtT[d*BQ + b];
    __syncthreads();
    if (tid < KTOP) {
        int idx = chosenI[tid];
        float sc = -FLT_MAX;
        if (idx >= 0 && idx < NENT) {
            const float* er = E + (size_t)idx*DDIM;
            float acc = 0.f;
            #pragma unroll 8
            for (int d = 0; d < DDIM; d += 4) {
                float4 v = *(const float4*)(er + d);
                acc += v.x*tgl[d+0];
                acc += v.y*tgl[d+1];
                acc += v.z*tgl[d+2];
                acc += v.w*tgl[d+3];
            }
            sc = acc;
        }
        partS[((size_t)b*NSLICE + sl)*KTOP + tid] = sc;
    }
}

// ---------------------------------------------------------------------------
// K4b: final top-10 via PARALLEL rank computation over the 160-entry pool.
// ---------------------------------------------------------------------------
__global__ __launch_bounds__(256) void k_merge(
    const float* __restrict__ partS, const int* __restrict__ partI,
    float* __restrict__ out)
{
    __shared__ float sc2[NSLICE*KTOP];
    __shared__ int   ix2[NSLICE*KTOP];
    int b = blockIdx.x, tid = threadIdx.x;
    if (tid < NSLICE*KTOP) {
        sc2[tid] = partS[(size_t)b*NSLICE*KTOP + tid];
        ix2[tid] = partI[(size_t)b*NSLICE*KTOP + tid];
    }
    __syncthreads();
    if (tid < NSLICE*KTOP) {
        float mv = sc2[tid]; int mi = ix2[tid];
        int rank = 0;
        #pragma unroll 8
        for (int i = 0; i < NSLICE*KTOP; i++) {
            float v = sc2[i]; int id = ix2[i];
            bool beats = (v > mv) ||
                         (v == mv && (id < mi || (id == mi && i < tid)));
            rank += beats ? 1 : 0;
        }
        if (rank < KTOP) {
            out[b*KTOP + rank]           = (float)mi;
            out[BQ*KTOP + b*KTOP + rank] = mv;
        }
    }
}

// ---------------------------------------------------------------------------
extern "C" void kernel_launch(void* const* d_in, const int* in_sizes, int n_in,
                              void* d_out, int out_size, void* d_ws, size_t ws_size,
                              hipStream_t stream)
{
    const int*   head = (const int*)d_in[0];
    const int*   rel  = (const int*)d_in[1];
    const float* E    = (const float*)d_in[2];
    const float* Rm   = (const float*)d_in[3];
    const float* proj = (const float*)d_in[4];
    // d_in[5] = k (always 10)

    char* ws = (char*)d_ws;
    float*          tgtT   = (float*)(ws);                    // 65536 B
    unsigned*       thash  = (unsigned*)(ws + 65536);         // 1024 B
    unsigned*       ahash  = (unsigned*)(ws + 66560);         // 1.6 MB
    float*          scores = (float*)(ws + 1666560);          // 25.6 MB
    unsigned char*  dist8  = (unsigned char*)(ws + 27266560); // 6.4 MB
    int*            dsG    = (int*)(ws + 33666560);           // 256 B
    int*            ncG    = (int*)(ws + 33666816);           // 256 B
    float*          partS  = (float*)(ws + 33667072);         // 40960 B
    int*            partI  = (int*)(ws + 33708032);           // 40960 B
    unsigned short* histG  = (unsigned short*)(ws + 33748992);// 270336 B
    unsigned short* Whi    = (unsigned short*)(ws + 34019328);// 98304 B
    unsigned short* Wmid   = (unsigned short*)(ws + 34117632);// 98304 B
    unsigned short* Wlo    = (unsigned short*)(ws + 34215936);// 98304 B
    float*          out    = (float*)d_out;

    hipLaunchKernelGGL(k_prep, dim3(192), dim3(256), 0, stream,
                       head, rel, E, Rm, proj, tgtT, thash, Whi, Wmid, Wlo);
    hipLaunchKernelGGL(k_gemm, dim3((NENT + TILE_E - 1)/TILE_E), dim3(256), 0, stream,
                       E, Whi, Wmid, Wlo, ahash, scores);
    hipLaunchKernelGGL(k_dist, dim3(NSLICE, BQ), dim3(256), 0, stream,
                       ahash, thash, dist8, histG);
    hipLaunchKernelGGL(k_cut, dim3(BQ), dim3(64), 0, stream,
                       dist8, histG, dsG, ncG);
    hipLaunchKernelGGL(k_part, dim3(NSLICE, BQ), dim3(256), 0, stream,
                       dist8, scores, dsG, ncG, tgtT, E, partS, partI);
    hipLaunchKernelGGL(k_merge, dim3(BQ), dim3(256), 0, stream,
                       partS, partI, out);
}

// Round 6
// 318.395 us; speedup vs baseline: 1.0136x; 1.0136x over previous
//
#include <hip/hip_runtime.h>
#include <hip/hip_bf16.h>
#include <float.h>

// Problem constants (fixed by the reference)
constexpr int NENT  = 100000;
constexpr int DDIM  = 256;
constexpr int BQ    = 64;
constexpr int CANDN = 10000;
constexpr int KTOP  = 10;
constexpr int NSLICE = 16;
constexpr int SLICE  = 6272;    // 16*6272 = 100352 >= NENT, multiple of 4 (and of 128)
constexpr int HPAD   = 132;     // histG per-(b,s) stride

typedef short v8s __attribute__((ext_vector_type(8)));   // 8 bf16 (4 VGPRs)
typedef float v4f __attribute__((ext_vector_type(4)));   // MFMA accumulator

// 3-way split: x ~= b0 + b1 + b2 (bf16 each), residual ~2^-21 |x|
__device__ inline void split3(float x, unsigned short& h0, unsigned short& h1,
                              unsigned short& h2) {
    unsigned t0 = __float_as_uint(x) & 0xffff0000u;
    float r1 = x - __uint_as_float(t0);
    unsigned t1 = __float_as_uint(r1) & 0xffff0000u;
    float r2 = r1 - __uint_as_float(t1);
    h0 = (unsigned short)(t0 >> 16);
    h1 = (unsigned short)(t1 >> 16);
    h2 = (unsigned short)(__float_as_uint(r2) >> 16);
}

// split 8 fp32 (two float4 slots in LDS) into three bf16x8 fragments
__device__ inline void split8p(const float* p0, const float* p1,
                               v8s& o0, v8s& o1, v8s& o2) {
    union { v8s v; unsigned short u[8]; } r0, r1, r2;
    float4 f0 = *(const float4*)p0;
    float4 f1 = *(const float4*)(p1);
    float av[8] = {f0.x, f0.y, f0.z, f0.w, f1.x, f1.y, f1.z, f1.w};
    #pragma unroll
    for (int j = 0; j < 8; j++)
        split3(av[j], r0.u[j], r1.u[j], r2.u[j]);
    o0 = r0.v; o1 = r1.v; o2 = r2.v;
}

// async global->LDS, 16B per lane; LDS dest is wave-uniform base + lane*16
__device__ inline void stage16(const float* g, float* l) {
    __builtin_amdgcn_global_load_lds(
        (const __attribute__((address_space(1))) void*)g,
        (__attribute__((address_space(3))) void*)l, 16, 0, 0);
}

// ---------------------------------------------------------------------------
// K1 (fused): blocks 0..127: proj column -> W planes.
//             blocks 128..191: target b = blk-128 -> tgtT, W col 128+b, thash.
// ---------------------------------------------------------------------------
__global__ __launch_bounds__(256) void k_prep(
    const int* __restrict__ head, const int* __restrict__ rel,
    const float* __restrict__ E, const float* __restrict__ Rm,
    const float* __restrict__ proj,
    float* __restrict__ tgtT, unsigned* __restrict__ thash,
    unsigned short* __restrict__ Whi, unsigned short* __restrict__ Wmid,
    unsigned short* __restrict__ Wlo)
{
    __shared__ float tg[DDIM];
    int blk = blockIdx.x;
    int tid = threadIdx.x;    // 256, one d each
    if (blk < 128) {
        int c = blk, d = tid;
        float x = proj[((c >> 5)*DDIM + d)*32 + (c & 31)];
        unsigned short h0, h1, h2;
        split3(x, h0, h1, h2);
        Whi [c*DDIM + d] = h0;
        Wmid[c*DDIM + d] = h1;
        Wlo [c*DDIM + d] = h2;
    } else {
        int b = blk - 128;
        int h = head[b], r = rel[b];
        int d = tid;
        float v = E[h*DDIM + d] * Rm[r*DDIM + d];
        tg[d] = v;
        tgtT[d*BQ + b] = v;
        unsigned short h0, h1, h2;
        split3(v, h0, h1, h2);
        int c = 128 + b;
        Whi [c*DDIM + d] = h0;
        Wmid[c*DDIM + d] = h1;
        Wlo [c*DDIM + d] = h2;
        __syncthreads();
        if (tid < 128) {
            int t = tid >> 5, hh = tid & 31;
            float acc = 0.f;
            #pragma unroll 8
            for (int dd = 0; dd < DDIM; dd++)
                acc += tg[dd] * proj[(t*DDIM + dd)*32 + hh];
            unsigned long long m = __ballot(acc > 0.0f);
            int lane = tid & 63, w = tid >> 6;
            if (lane == 0) {
                thash[b*4 + w*2 + 0] = (unsigned)(m & 0xffffffffull);
                thash[b*4 + w*2 + 1] = (unsigned)(m >> 32);
            }
        }
    }
}

// ---------------------------------------------------------------------------
// K2: MFMA bf16x3 (6-product) GEMM.  out[n][c] = sum_d E[n][d] * W[c][d]
//   cols 0..127 -> sign bits packed to ahash[n][4]; cols 128..191 -> scores.
// R4 structure (best measured, 111 us): TILE_E=128, BK=32, A double-buffered
// via global_load_lds w=16 + 16B-unit XOR swizzle (both-sides), B from global
// (L2-resident), one barrier per chunk. Numerics: exact accumulation order.
// Do not perturb: BK=64 (R5) and TILE_E=64 (R3) both measured slower.
// ---------------------------------------------------------------------------
constexpr int TILE_E = 128;

__global__ __launch_bounds__(256, 2) void k_gemm(
    const float* __restrict__ E,
    const unsigned short* __restrict__ Whi, const unsigned short* __restrict__ Wmid,
    const unsigned short* __restrict__ Wlo,
    unsigned* __restrict__ ahash, float* __restrict__ scores)
{
    __shared__ __align__(16) float Af[2][TILE_E*32];   // 2 x 16 KiB
    unsigned short* bitsHalf = (unsigned short*)Af;    // aliased after compute

    int tid = threadIdx.x;
    int l = tid & 63, w = tid >> 6;
    int wm = w >> 1, wn = w & 1;
    int m = l & 15, quad = l >> 4;
    int n0 = blockIdx.x * TILE_E;

    // --- per-thread staging source pointers (4 wave-instructions/chunk) ---
    // linear LDS unit U = it*256 + tid; row = U>>3, slot = U&7,
    // source unit = slot ^ (row&7)  (both-sides swizzle, LDS dest linear)
    const float* gsrc[4];
    #pragma unroll
    for (int it = 0; it < 4; it++) {
        int U = it*256 + tid;           // 0..1023
        int row = U >> 3;               // 0..127
        int us  = (U & 7) ^ (row & 7);
        int n = n0 + row; if (n >= NENT) n = NENT - 1;
        gsrc[it] = E + (size_t)n*DDIM + us*4;
    }

    // --- A-fragment LDS read offsets (floats), conflict-free swizzled ---
    int offA0[4], offA1[4];
    #pragma unroll
    for (int a = 0; a < 4; a++) {
        int row = wm*64 + a*16 + m;
        offA0[a] = row*32 + (((2*quad)    ) ^ (m & 7))*4;
        offA1[a] = row*32 + (((2*quad) | 1) ^ (m & 7))*4;
    }

    // --- B column base offsets (halfwords into W planes) ---
    int colOff[6];
    #pragma unroll
    for (int c = 0; c < 6; c++)
        colOff[c] = (wn*96 + c*16 + m)*DDIM + quad*8;

    v4f acc[4][6];
    #pragma unroll
    for (int a = 0; a < 4; a++)
        #pragma unroll
        for (int c = 0; c < 6; c++)
            acc[a][c] = (v4f)0.0f;

    // prologue: stage chunk 0 into buffer 0
    #pragma unroll
    for (int it = 0; it < 4; it++)
        stage16(gsrc[it], &Af[0][(it*256 + w*64)*4]);
    __syncthreads();

    int bb = 0;
    for (int ch = 0; ch < DDIM/32; ch++) {
        // issue next-chunk stage first (latency hides under compute below)
        if (ch + 1 < DDIM/32) {
            #pragma unroll
            for (int it = 0; it < 4; it++)
                stage16(gsrc[it] + (ch + 1)*32, &Af[bb ^ 1][(it*256 + w*64)*4]);
        }

        // A fragments: fp32 from LDS (swizzled, conflict-free), split in-register
        v8s a0[4], a1[4], a2[4];
        #pragma unroll
        for (int a = 0; a < 4; a++)
            split8p(&Af[bb][offA0[a]], &Af[bb][offA1[a]], a0[a], a1[a], a2[a]);

        // B fragments straight from global (L2-warm), 6-product MFMA
        int d0 = ch*32;
        #pragma unroll
        for (int c = 0; c < 6; c++) {
            int co = colOff[c] + d0;
            v8s b0 = *(const v8s*)(Whi  + co);
            v8s b1 = *(const v8s*)(Wmid + co);
            v8s b2 = *(const v8s*)(Wlo  + co);
            #pragma unroll
            for (int a = 0; a < 4; a++) {
                acc[a][c] = __builtin_amdgcn_mfma_f32_16x16x32_bf16(a2[a], b0, acc[a][c], 0, 0, 0);
                acc[a][c] = __builtin_amdgcn_mfma_f32_16x16x32_bf16(a0[a], b2, acc[a][c], 0, 0, 0);
                acc[a][c] = __builtin_amdgcn_mfma_f32_16x16x32_bf16(a1[a], b1, acc[a][c], 0, 0, 0);
                acc[a][c] = __builtin_amdgcn_mfma_f32_16x16x32_bf16(a1[a], b0, acc[a][c], 0, 0, 0);
                acc[a][c] = __builtin_amdgcn_mfma_f32_16x16x32_bf16(a0[a], b1, acc[a][c], 0, 0, 0);
                acc[a][c] = __builtin_amdgcn_mfma_f32_16x16x32_bf16(a0[a], b0, acc[a][c], 0, 0, 0);
            }
        }
        __syncthreads();   // drains vmcnt(0): next buffer staged + safe reuse
        bb ^= 1;
    }

    // ---- epilogue: C/D layout col=lane&15, row=quad*4+reg ----
    #pragma unroll
    for (int c = 0; c < 6; c++) {
        int ct = wn*6 + c;                 // global col-tile 0..11
        if (ct < 8) {
            #pragma unroll
            for (int a = 0; a < 4; a++) {
                #pragma unroll
                for (int r = 0; r < 4; r++) {
                    unsigned long long mb = __ballot(acc[a][c][r] > 0.0f);
                    if (m == 0) {
                        int rowl = wm*64 + a*16 + quad*4 + r;
                        bitsHalf[rowl*8 + ct] = (unsigned short)(mb >> (quad*16));
                    }
                }
            }
        } else {
            int b = ct*16 - 128 + m;       // query index 0..63
            #pragma unroll
            for (int a = 0; a < 4; a++) {
                int nb = n0 + wm*64 + a*16 + quad*4;
                if (nb < NENT)
                    *(float4*)(scores + (size_t)b*NENT + nb) = *(float4*)&acc[a][c];
            }
        }
    }
    __syncthreads();
    if (tid < TILE_E) {
        int n = n0 + tid;
        if (n < NENT)
            *(uint4*)(ahash + (size_t)n*4) = *(const uint4*)&bitsHalf[tid*8];
    }
}

// ---------------------------------------------------------------------------
// K3a: per-(query,slice) distance bytes + slice histogram.
// 8-way lane-interleaved histograms (hist[bin][tid&7]).
// ---------------------------------------------------------------------------
__global__ __launch_bounds__(256) void k_dist(
    const unsigned* __restrict__ ahash, const unsigned* __restrict__ thash,
    unsigned char* __restrict__ dist8, unsigned short* __restrict__ histG)
{
    __shared__ unsigned hist[HPAD][8];
    int s = blockIdx.x, b = blockIdx.y, tid = threadIdx.x;
    int lv = tid & 7;
    for (int i = tid; i < 8*HPAD; i += 256) ((unsigned*)hist)[i] = 0u;
    uint4 tw = *(const uint4*)(thash + b*4);
    __syncthreads();
    int n0 = s*SLICE;
    int n1 = n0 + SLICE; if (n1 > NENT) n1 = NENT;
    unsigned char* drow = dist8 + (size_t)b*NENT;
    for (int n = n0 + tid*4; n < n1; n += 1024) {
        int dv[4];
        #pragma unroll
        for (int i = 0; i < 4; i++) {
            uint4 a = *(const uint4*)(ahash + (size_t)(n+i)*4);
            dv[i] = __popc(a.x^tw.x) + __popc(a.y^tw.y) +
                    __popc(a.z^tw.z) + __popc(a.w^tw.w);
            atomicAdd(&hist[dv[i]][lv], 1u);
        }
        uchar4 o = make_uchar4((unsigned char)dv[0], (unsigned char)dv[1],
                               (unsigned char)dv[2], (unsigned char)dv[3]);
        *(uchar4*)(drow + n) = o;
    }
    __syncthreads();
    unsigned short* hrow = histG + ((size_t)b*NSLICE + s)*HPAD;
    for (int i = tid; i < 129; i += 256) {
        unsigned t = 0;
        #pragma unroll
        for (int v = 0; v < 8; v++) t += hist[i][v];
        hrow[i] = (unsigned short)t;
    }
}

// ---------------------------------------------------------------------------
// K4a: per-(query, slice) top-10 pool builder, with the cut computation
// (former k_cut) FUSED in: every block redundantly computes (ds, nc) from
// histG + a wave-0 ballot scan of slice slS -- identical logic, runs in
// parallel across 1024 blocks instead of serializing on a 64-block kernel.
// Then: threshold top-10 selection + EXACT fp32 rescore of winners.
// ---------------------------------------------------------------------------
__global__ __launch_bounds__(256) void k_part(
    const unsigned char* __restrict__ dist8, const float* __restrict__ scores,
    const unsigned short* __restrict__ histG,
    const float* __restrict__ tgtT, const float* __restrict__ E,
    float* __restrict__ partS, int* __restrict__ partI)
{
    __shared__ unsigned histT[HPAD];
    __shared__ int dsS, slS, rpS, ncS;
    __shared__ float ls[256];
    __shared__ int   li[256];
    __shared__ float ps[112];
    __shared__ int   pi[112];
    __shared__ int   pcnt;
    __shared__ float TsS; __shared__ int TiS;
    __shared__ int   chosenI[KTOP];
    __shared__ float tgl[DDIM];

    int sl = blockIdx.x, b = blockIdx.y, tid = threadIdx.x;
    const unsigned char* drow = dist8 + (size_t)b*NENT;
    const float* srow = scores + (size_t)b*NENT;

    // ---- fused cut: total histogram -> d*, quota R; slice prefix -> slS,rp ----
    for (int d = tid; d < 129; d += 256) {
        unsigned sum = 0;
        for (int s = 0; s < NSLICE; s++)
            sum += histG[((size_t)b*NSLICE + s)*HPAD + d];
        histT[d] = sum;
    }
    if (tid == 0) ncS = -1;
    __syncthreads();
    if (tid == 0) {
        unsigned cum = 0; int dss = 128; unsigned R = 1;
        for (int d = 0; d < 129; d++) {
            unsigned c = cum + histT[d];
            if (c >= (unsigned)CANDN) { dss = d; R = (unsigned)CANDN - cum; break; }
            cum = c;
        }
        dsS = dss;
        unsigned acc = 0; slS = NSLICE - 1; rpS = 1;
        for (int s = 0; s < NSLICE; s++) {
            unsigned c = histG[((size_t)b*NSLICE + s)*HPAD + dss];
            if (acc + c >= R) { slS = s; rpS = (int)(R - acc); break; }
            acc += c;
        }
    }
    __syncthreads();
    // wave-0 ballot scan of slice slS for the rp-th entity with dist == ds
    if (tid < 64) {
        int dss = dsS;
        unsigned Rp = (unsigned)rpS;
        int sBase = slS*SLICE;
        int sEnd = sBase + SLICE; if (sEnd > NENT) sEnd = NENT;
        unsigned cnt = 0;
        for (int base = sBase; base < sEnd; base += 256) {
            unsigned char qa[4];
            #pragma unroll
            for (int s4 = 0; s4 < 4; s4++) {
                int n = base + s4*64 + tid;
                qa[s4] = (n < sEnd) ? drow[n] : (unsigned char)255;
            }
            bool done = false;
            #pragma unroll
            for (int s4 = 0; s4 < 4; s4++) {
                bool eq = (qa[s4] == (unsigned char)dss);
                unsigned long long mm = __ballot(eq);
                unsigned c = __popcll(mm);
                if (cnt + c >= Rp) {
                    unsigned pre = __popcll(mm & ((1ull << tid) - 1ull));
                    if (eq && (cnt + pre + 1u == Rp)) ncS = base + s4*64 + tid;
                    done = true; break;
                }
                cnt += c;
            }
            if (done) break;
        }
    }
    __syncthreads();
    int ds = dsS, nc = ncS;

    // ---- per-thread top-10 scan over this block's slice ----
    int n0 = sl*SLICE;
    int n1 = n0 + SLICE; if (n1 > NENT) n1 = NENT;

    float topS[KTOP]; int topI[KTOP];
    #pragma unroll
    for (int i = 0; i < KTOP; i++) { topS[i] = -FLT_MAX; topI[i] = 0x7fffffff; }

    for (int n = n0 + tid*4; n < n1; n += 1024) {
        uchar4 dv = *(const uchar4*)(drow + n);
        unsigned char da[4] = {dv.x, dv.y, dv.z, dv.w};
        #pragma unroll
        for (int i = 0; i < 4; i++) {
            int d = da[i];
            int nn = n + i;
            if (d < ds || (d == ds && nn <= nc)) {
                float sc = srow[nn];
                if (sc > topS[KTOP-1]) {
                    int p = KTOP - 1;
                    while (p > 0 && topS[p-1] < sc) {
                        topS[p] = topS[p-1]; topI[p] = topI[p-1]; p--;
                    }
                    topS[p] = sc; topI[p] = nn;
                }
            }
        }
    }

    // ---- threshold selection (3 barriers) ----
    ls[tid] = topS[0]; li[tid] = topI[0];
    if (tid == 0) pcnt = 0;
    if (tid < 112) { ps[tid] = -FLT_MAX; pi[tid] = 0x7fffffff; }
    __syncthreads();

    float mv = topS[0]; int mi = topI[0];
    int rank = 0;
    for (int i = 0; i < 256; i++) {
        float v = ls[i]; int id = li[i];
        rank += (v > mv || (v == mv && id < mi)) ? 1 : 0;
    }
    if (rank == 9 || (rank < 9 && mi == 0x7fffffff)) { TsS = mv; TiS = mi; }
    __syncthreads();
    float ts = TsS; int ti = TiS;

    if (!(ts > mv || (ts == mv && ti < mi))) {
        #pragma unroll
        for (int j = 0; j < KTOP; j++) {
            float sj = topS[j]; int ij = topI[j];
            if (ij == 0x7fffffff) break;
            if (sj > ts || (sj == ts && ij <= ti)) {
                int p = atomicAdd(&pcnt, 1);
                ps[p] = sj; pi[p] = ij;
            } else break;
        }
    }
    __syncthreads();

    if (tid < 112) {
        float s = ps[tid]; int id = pi[tid];
        int r = 0;
        for (int i = 0; i < 112; i++) {
            float v = ps[i]; int iv = pi[i];
            bool beats = (v > s) || (v == s && (iv < id || (iv == id && i < tid)));
            r += beats ? 1 : 0;
        }
        if (r < KTOP) {
            chosenI[r] = id;
            partI[((size_t)b*NSLICE + sl)*KTOP + r] = id;
        }
    }

    // exact fp32 rescore of the 10 winners (order-preserving sequential dot)
    for (int d = tid; d < DDIM; d += 256) tgl[d] = tgtT[d*BQ + b];
    __syncthreads();
    if (tid < KTOP) {
        int idx = chosenI[tid];
        float sc = -FLT_MAX;
        if (idx >= 0 && idx < NENT) {
            const float* er = E + (size_t)idx*DDIM;
            float acc = 0.f;
            #pragma unroll 8
            for (int d = 0; d < DDIM; d += 4) {
                float4 v = *(const float4*)(er + d);
                acc += v.x*tgl[d+0];
                acc += v.y*tgl[d+1];
                acc += v.z*tgl[d+2];
                acc += v.w*tgl[d+3];
            }
            sc = acc;
        }
        partS[((size_t)b*NSLICE + sl)*KTOP + tid] = sc;
    }
}

// ---------------------------------------------------------------------------
// K4b: final top-10 via PARALLEL rank computation over the 160-entry pool.
// ---------------------------------------------------------------------------
__global__ __launch_bounds__(256) void k_merge(
    const float* __restrict__ partS, const int* __restrict__ partI,
    float* __restrict__ out)
{
    __shared__ float sc2[NSLICE*KTOP];
    __shared__ int   ix2[NSLICE*KTOP];
    int b = blockIdx.x, tid = threadIdx.x;
    if (tid < NSLICE*KTOP) {
        sc2[tid] = partS[(size_t)b*NSLICE*KTOP + tid];
        ix2[tid] = partI[(size_t)b*NSLICE*KTOP + tid];
    }
    __syncthreads();
    if (tid < NSLICE*KTOP) {
        float mv = sc2[tid]; int mi = ix2[tid];
        int rank = 0;
        #pragma unroll 8
        for (int i = 0; i < NSLICE*KTOP; i++) {
            float v = sc2[i]; int id = ix2[i];
            bool beats = (v > mv) ||
                         (v == mv && (id < mi || (id == mi && i < tid)));
            rank += beats ? 1 : 0;
        }
        if (rank < KTOP) {
            out[b*KTOP + rank]           = (float)mi;
            out[BQ*KTOP + b*KTOP + rank] = mv;
        }
    }
}

// ---------------------------------------------------------------------------
extern "C" void kernel_launch(void* const* d_in, const int* in_sizes, int n_in,
                              void* d_out, int out_size, void* d_ws, size_t ws_size,
                              hipStream_t stream)
{
    const int*   head = (const int*)d_in[0];
    const int*   rel  = (const int*)d_in[1];
    const float* E    = (const float*)d_in[2];
    const float* Rm   = (const float*)d_in[3];
    const float* proj = (const float*)d_in[4];
    // d_in[5] = k (always 10)

    char* ws = (char*)d_ws;
    float*          tgtT   = (float*)(ws);                    // 65536 B
    unsigned*       thash  = (unsigned*)(ws + 65536);         // 1024 B
    unsigned*       ahash  = (unsigned*)(ws + 66560);         // 1.6 MB
    float*          scores = (float*)(ws + 1666560);          // 25.6 MB
    unsigned char*  dist8  = (unsigned char*)(ws + 27266560); // 6.4 MB
    float*          partS  = (float*)(ws + 33667072);         // 40960 B
    int*            partI  = (int*)(ws + 33708032);           // 40960 B
    unsigned short* histG  = (unsigned short*)(ws + 33748992);// 270336 B
    unsigned short* Whi    = (unsigned short*)(ws + 34019328);// 98304 B
    unsigned short* Wmid   = (unsigned short*)(ws + 34117632);// 98304 B
    unsigned short* Wlo    = (unsigned short*)(ws + 34215936);// 98304 B
    float*          out    = (float*)d_out;

    hipLaunchKernelGGL(k_prep, dim3(192), dim3(256), 0, stream,
                       head, rel, E, Rm, proj, tgtT, thash, Whi, Wmid, Wlo);
    hipLaunchKernelGGL(k_gemm, dim3((NENT + TILE_E - 1)/TILE_E), dim3(256), 0, stream,
                       E, Whi, Wmid, Wlo, ahash, scores);
    hipLaunchKernelGGL(k_dist, dim3(NSLICE, BQ), dim3(256), 0, stream,
                       ahash, thash, dist8, histG);
    hipLaunchKernelGGL(k_part, dim3(NSLICE, BQ), dim3(256), 0, stream,
                       dist8, scores, histG, tgtT, E, partS, partI);
    hipLaunchKernelGGL(k_merge, dim3(BQ), dim3(256), 0, stream,
                       partS, partI, out);
}